// Round 9
// baseline (247.714 us; speedup 1.0000x reference)
//
#include <hip/hip_runtime.h>

#define Bdim   4096
#define INdim  4096
#define OUTdim 2048
#define Knz    32

typedef float  f4  __attribute__((ext_vector_type(4)));
typedef short  s4  __attribute__((ext_vector_type(4)));

// f32 -> bf16 round-to-nearest-even
__device__ inline unsigned short f2bf(float f) {
  unsigned u = __float_as_uint(f);
  u += 0x7fffu + ((u >> 16) & 1u);
  return (unsigned short)(u >> 16);
}

// Kernel 1: xT[i][b] = bf16(x[b][i]).  64x64 tiles via LDS.  96 MB stream at
// HBM floor (~15-20us).  nt on both sides: keep the stream out of L2.
__global__ __launch_bounds__(256) void k_transpose(const float* __restrict__ x,
                                                   unsigned short* __restrict__ xT) {
  __shared__ float tile[64][65];
  const int bi = blockIdx.x;      // 64-row tile (b dim)
  const int ii = blockIdx.y;      // 64-col tile (IN dim)
  const int t = threadIdx.x;
  const int r = t >> 4;           // 0..15
  const int c = t & 15;           // 0..15
#pragma unroll
  for (int rr = 0; rr < 64; rr += 16) {
    const f4 v = __builtin_nontemporal_load(reinterpret_cast<const f4*>(
        &x[(size_t)(bi * 64 + rr + r) * INdim + ii * 64 + c * 4]));
    tile[rr + r][c * 4 + 0] = v.x;
    tile[rr + r][c * 4 + 1] = v.y;
    tile[rr + r][c * 4 + 2] = v.z;
    tile[rr + r][c * 4 + 3] = v.w;
  }
  __syncthreads();
#pragma unroll
  for (int rr = 0; rr < 64; rr += 16) {
    const int il = rr + r;
    s4 o;
    o.x = (short)f2bf(tile[c * 4 + 0][il]);
    o.y = (short)f2bf(tile[c * 4 + 1][il]);
    o.z = (short)f2bf(tile[c * 4 + 2][il]);
    o.w = (short)f2bf(tile[c * 4 + 3][il]);
    __builtin_nontemporal_store(o, reinterpret_cast<s4*>(
        &xT[(size_t)(ii * 64 + il) * Bdim + bi * 64 + c * 4]));
  }
}

// Kernel 2: gather-dot.  R9: REQUEST WIDTH is the lever.
// R1 (7 waves/SIMD, dword) and R8 (3 waves/SIMD, dwordx2, 4-deep) both hit
// ~59us => limiter is per-CU outstanding-request capacity, not wave count or
// ILP depth alone. Fix: dwordx4 gathers (1KB/wave-request, 2x R8; 512K total
// requests, half of R8).
// Geometry: lane -> 8 consecutive b => b-tile = 512 (= XCD slice, 4MB L2);
//   1024 blocks: xcd = wg&7 -> bt; op = wg>>3 (128 o-panels of 16);
//   wave w -> 4 o. 1024 blocks = 4/CU -> entire grid co-resident at
//   4 waves/SIMD (no tail).
// Addressing (PROVEN R8): wave's 128 cols/vals preloaded into 2+2 VGPRs;
//   readlane at compile-time lane -> uniform -> SGPR SALU address; gather is
//   saddr-form global_load_dwordx4; per-load VGPR cost = 4 dest regs only.
// Window: 2-deep x 8 loads (64 dest regs; live ~115 regs). Consume-side FMA
//   block (~290cyc) covers L2 latency. sched_barrier stops deeper hoisting
//   (R8-proven). NO launch_bounds waves-arg (R4/R6: halves budget -> spill).
__global__ __launch_bounds__(256) void k_gather(const unsigned short* __restrict__ xT,
                                                const int* __restrict__ cols,
                                                const float* __restrict__ values,
                                                float* __restrict__ out) {
  const int wg = blockIdx.x;                 // 0..1023
  const int bt = wg & 7;                     // b-tile == XCD slice (512 b, 4MB)
  const int op = wg >> 3;                    // 0..127 o-panels of 16
  const int w = threadIdx.x >> 6;            // wave 0..3 -> o sub-panel
  const int l = threadIdx.x & 63;            // lane -> 8 consecutive b
  const int o0 = op * 16 + w * 4;

  // Preload this wave's 128 cols / 128 values into 2+2 VGPRs (coalesced).
  const int* __restrict__ cw = cols + o0 * Knz;
  const float* __restrict__ vw = values + o0 * Knz;
  const int c0i = cw[l];
  const int c1i = cw[64 + l];
  const int v0i = __float_as_int(vw[l]);
  const int v1i = __float_as_int(vw[64 + l]);

  const unsigned short* __restrict__ xtb = xT + bt * 512;  // wave-uniform base
  const int le = l * 8;                                    // lane elem offset

  float acc[4][8];                           // [oc][b-sub], static idx -> regs
#pragma unroll
  for (int i = 0; i < 4; ++i)
#pragma unroll
    for (int j = 0; j < 8; ++j) acc[i][j] = 0.f;

  uint4 win[2][8];                           // 2-deep rotating load window

  // Prologue: batch 0 in flight (8 x dwordx4).
#pragma unroll
  for (int k = 0; k < 8; ++k) {
    const int col = __builtin_amdgcn_readlane(c0i, k);
    win[0][k] = *reinterpret_cast<const uint4*>(xtb + (size_t)col * Bdim + le);
  }

  // 16 batches of 8 gathers: g = j*8+k in [0,128); oc = j>>2.
#pragma unroll
  for (int j = 0; j < 16; ++j) {
    if (j < 15) {
      const int jn = j + 1;
#pragma unroll
      for (int k = 0; k < 8; ++k) {
        const int g = jn * 8 + k;
        const int col = (g < 64) ? __builtin_amdgcn_readlane(c0i, g)
                                 : __builtin_amdgcn_readlane(c1i, g - 64);
        win[jn & 1][k] = *reinterpret_cast<const uint4*>(xtb + (size_t)col * Bdim + le);
      }
    }
    const int oc = j >> 2;
#pragma unroll
    for (int k = 0; k < 8; ++k) {
      const int g = j * 8 + k;
      const float val = __int_as_float((g < 64) ? __builtin_amdgcn_readlane(v0i, g)
                                                : __builtin_amdgcn_readlane(v1i, g - 64));
      const uint4 gu = win[j & 1][k];
      acc[oc][0] = fmaf(__uint_as_float(gu.x << 16),         val, acc[oc][0]);
      acc[oc][1] = fmaf(__uint_as_float(gu.x & 0xffff0000u), val, acc[oc][1]);
      acc[oc][2] = fmaf(__uint_as_float(gu.y << 16),         val, acc[oc][2]);
      acc[oc][3] = fmaf(__uint_as_float(gu.y & 0xffff0000u), val, acc[oc][3]);
      acc[oc][4] = fmaf(__uint_as_float(gu.z << 16),         val, acc[oc][4]);
      acc[oc][5] = fmaf(__uint_as_float(gu.z & 0xffff0000u), val, acc[oc][5]);
      acc[oc][6] = fmaf(__uint_as_float(gu.w << 16),         val, acc[oc][6]);
      acc[oc][7] = fmaf(__uint_as_float(gu.w & 0xffff0000u), val, acc[oc][7]);
    }
    __builtin_amdgcn_sched_barrier(0);
  }

  // 8 rows x 16B cached stores; each 64B out line (16 o) completed by the
  // block's 4 waves (R5/R8-proven: no write amplification).
  const int b0 = bt * 512 + le;
#pragma unroll
  for (int r = 0; r < 8; ++r) {
    *reinterpret_cast<f4*>(&out[(size_t)(b0 + r) * OUTdim + o0]) =
        (f4){acc[0][r], acc[1][r], acc[2][r], acc[3][r]};
  }
}

// Correct-but-slow fallback if ws can't hold xT (32 MB).
__global__ __launch_bounds__(256) void k_naive(const float* __restrict__ x,
                                               const float* __restrict__ values,
                                               const int* __restrict__ cols,
                                               float* __restrict__ out) {
  const size_t id = (size_t)blockIdx.x * 256 + threadIdx.x;
  const int o = (int)(id % OUTdim);
  const int b = (int)(id / OUTdim);
  float a = 0.f;
  for (int k = 0; k < Knz; ++k) {
    const int col = cols[o * Knz + k];
    a = fmaf(x[(size_t)b * INdim + col], values[o * Knz + k], a);
  }
  out[id] = a;
}

extern "C" void kernel_launch(void* const* d_in, const int* in_sizes, int n_in,
                              void* d_out, int out_size, void* d_ws, size_t ws_size,
                              hipStream_t stream) {
  const float* x = (const float*)d_in[0];
  const float* values = (const float*)d_in[1];
  const int* cols = (const int*)d_in[2];
  float* out = (float*)d_out;

  const size_t need = (size_t)INdim * Bdim * sizeof(unsigned short);  // 32 MB
  if (ws_size >= need) {
    unsigned short* xT = (unsigned short*)d_ws;
    k_transpose<<<dim3(64, 64), 256, 0, stream>>>(x, xT);
    k_gather<<<1024, 256, 0, stream>>>(xT, cols, values, out);
  } else {
    k_naive<<<(Bdim * (size_t)OUTdim) / 256, 256, 0, stream>>>(x, values, cols, out);
  }
}